// Round 6
// baseline (1806.541 us; speedup 1.0000x reference)
//
#include <hip/hip_runtime.h>
#include <hip/hip_bf16.h>

#define B_ 4
#define S_ 512
#define D_ 512
#define I_ 1024
#define C_ 32
#define NC_ 16

// ---- ws layout (float offsets) ----
#define KBUF (B_*S_*D_)
#define STSZ (B_*I_*D_)
#define HSZ  (B_*I_*C_)
#define DOSZ (B_*C_*D_)
#define ZPSZ (B_*I_*C_)
#define OFF_K    0
#define OFF_V    (OFF_K + KBUF)
#define OFF_Q    (OFF_V + KBUF)
#define OFF_TH   (OFF_Q + KBUF)
#define OFF_AL   (OFF_TH + B_*S_)
#define OFF_ET   (OFF_AL + B_*S_)
#define OFF_KN2  (OFF_ET + B_*S_)
#define OFF_SLN  (OFF_KN2 + B_*S_)
#define OFF_MLN  (OFF_SLN + B_*D_)
#define OFF_H2   (OFF_MLN + B_*D_)
#define OFF_ZP   (OFF_H2 + 2*HSZ)       // 4 z-partials (D split)
#define OFF_DHP  (OFF_ZP + 4*ZPSZ)
#define OFF_DO   (OFF_DHP + HSZ)
#define OFF_DLN  (OFF_DO + DOSZ)
#define OFF_OBP  (OFF_DLN + DOSZ)       // 8 o-partials (I split)
#define OFF_SLAB (OFF_OBP + 8*DOSZ)
#define SLABSTR  256
#define OFF_TICK (OFF_SLAB + NC_*B_*SLABSTR)
#define OFF_FLAG (OFF_TICK + 64)
#define OFF_ORET (OFF_FLAG + 16)
#define OFF_BST  (OFF_ORET + KBUF)      // bf16 states (ushort*): SW1,MW1,SW2,MW2
#define OFF_HQ   OFF_K                  // alias, dead after chunk loop

__device__ __forceinline__ float bf2f(__hip_bfloat16 v){ return __bfloat162float(v); }
__device__ __forceinline__ float bfu2f(unsigned short u){ return __uint_as_float(((unsigned)u)<<16); }
__device__ __forceinline__ unsigned short f2bfu(float f){
  unsigned x = __float_as_uint(f);
  return (unsigned short)((x + 0x7FFFu + ((x>>16)&1u)) >> 16);
}
__device__ __forceinline__ float4 u42f4(ushort4 u){
  float4 r; r.x=bfu2f(u.x); r.y=bfu2f(u.y); r.z=bfu2f(u.z); r.w=bfu2f(u.w); return r;
}
__device__ __forceinline__ ushort4 f42u4(float4 v){
  ushort4 r; r.x=f2bfu(v.x); r.y=f2bfu(v.y); r.z=f2bfu(v.z); r.w=f2bfu(v.w); return r;
}
__device__ __forceinline__ float ldin(const void* p, size_t i, int f){
  return f ? ((const float*)p)[i] : bf2f(((const __hip_bfloat16*)p)[i]);
}
__device__ __forceinline__ float4 ld4g(const void* p, size_t i, int f){
  if(f) return ((const float4*)p)[i>>2];
  return u42f4(((const ushort4*)p)[i>>2]);
}

__device__ __forceinline__ float blockReduceSum(float v, float* sm){
  #pragma unroll
  for(int o=32;o>0;o>>=1) v += __shfl_down(v,o,64);
  int wid = threadIdx.x>>6, lane = threadIdx.x&63;
  __syncthreads();
  if(lane==0) sm[wid]=v;
  __syncthreads();
  return sm[0]+sm[1]+sm[2]+sm[3];
}

// ---------------- D0: runtime input-dtype detection ----------------
__global__ void d0_detect(const void* __restrict__ x, float* __restrict__ ws){
  __shared__ int cnt;
  if(threadIdx.x==0) cnt=0;
  __syncthreads();
  unsigned w = ((const unsigned*)x)[(size_t)threadIdx.x*931 + 17];
  int e = (w>>7)&0xFF;
  if(e>=110 && e<=140) atomicAdd(&cnt,1);
  __syncthreads();
  if(threadIdx.x==0) ((int*)(ws+OFF_FLAG))[0] = (cnt<32) ? 1 : 0;  // 1 => f32 inputs
}

// ---------------- P0: init states / slabs ----------------
__global__ void p0_init(float* __restrict__ ws, const void* __restrict__ w1,
                        const void* __restrict__ w2, const void* __restrict__ ln){
  int f = ((const int*)(ws+OFF_FLAG))[0];
  unsigned short* bst = (unsigned short*)(ws + OFF_BST);
  size_t id = (size_t)blockIdx.x*blockDim.x + threadIdx.x;
  size_t stride = (size_t)gridDim.x*blockDim.x;
  ushort4 z4 = {0,0,0,0};
  for(size_t t4=id; t4<(size_t)(STSZ/4); t4+=stride){
    size_t e4 = t4 % (size_t)(I_*D_/4);
    *(ushort4*)(bst + (size_t)STSZ + t4*4)   = f42u4(ld4g(w1, e4*4, f));  // MW1
    *(ushort4*)(bst + (size_t)3*STSZ + t4*4) = f42u4(ld4g(w2, e4*4, f));  // MW2
    *(ushort4*)(bst + t4*4) = z4;                                          // SW1
    *(ushort4*)(bst + (size_t)2*STSZ + t4*4) = z4;                         // SW2
  }
  for(size_t t=id; t<(size_t)(B_*D_); t+=stride){
    ws[OFF_MLN+t] = ldin(ln,t % D_,f);
    ws[OFF_SLN+t] = 0.f;
  }
  for(size_t t=id; t<(size_t)(NC_*B_*SLABSTR); t+=stride) ws[OFF_SLAB+t]=0.f;
  int* tick = (int*)(ws + OFF_TICK);
  for(size_t t=id; t<64; t+=stride) tick[t]=0;
}

// ---------------- P1a: k,v,q = silu(x@W^T) ----------------
__global__ void __launch_bounds__(256) p1a(const void* __restrict__ x,
                    const void* __restrict__ wk,
                    const void* __restrict__ wv,
                    const void* __restrict__ wq,
                    float* __restrict__ ws){
  int f = ((const int*)(ws+OFF_FLAG))[0];
  int pid = blockIdx.z;
  const void* W = (pid==0)?wk:((pid==1)?wv:wq);
  float* outp = ws + ((pid==0)?OFF_K:((pid==1)?OFF_V:OFF_Q));
  int r0 = blockIdx.x*64, j0 = blockIdx.y*64;
  __shared__ __align__(16) float xa[32][68], wa[32][68];
  float acc[4][4]={};
  int tx = threadIdx.x & 15, ty = threadIdx.x >> 4;
  for(int k0=0;k0<512;k0+=32){
    #pragma unroll
    for(int q=0;q<2;q++){
      int f4id = threadIdx.x + 256*q;
      int row = f4id>>3, kq = f4id&7;
      float4 v = ld4g(x, (size_t)(r0+row)*512 + k0 + kq*4, f);
      xa[kq*4+0][row]=v.x; xa[kq*4+1][row]=v.y; xa[kq*4+2][row]=v.z; xa[kq*4+3][row]=v.w;
      float4 w = ld4g(W, (size_t)(j0+row)*512 + k0 + kq*4, f);
      wa[kq*4+0][row]=w.x; wa[kq*4+1][row]=w.y; wa[kq*4+2][row]=w.z; wa[kq*4+3][row]=w.w;
    }
    __syncthreads();
    #pragma unroll
    for(int kk=0;kk<32;kk++){
      float4 a4 = *(float4*)&xa[kk][ty*4];
      float4 b4 = *(float4*)&wa[kk][tx*4];
      float a_[4]={a4.x,a4.y,a4.z,a4.w}, b_[4]={b4.x,b4.y,b4.z,b4.w};
      #pragma unroll
      for(int i=0;i<4;i++)
        #pragma unroll
        for(int j=0;j<4;j++) acc[i][j] += a_[i]*b_[j];
    }
    __syncthreads();
  }
  #pragma unroll
  for(int i=0;i<4;i++){
    float4 o4;
    float z0=acc[i][0], z1=acc[i][1], z2=acc[i][2], z3=acc[i][3];
    o4.x = z0/(1.f+expf(-z0)); o4.y = z1/(1.f+expf(-z1));
    o4.z = z2/(1.f+expf(-z2)); o4.w = z3/(1.f+expf(-z3));
    *(float4*)(outp + (size_t)(r0+ty*4+i)*512 + j0 + tx*4) = o4;
  }
}

// ---------------- P1b: rms(k),rms(q), |k|^2, gates ----------------
__global__ void __launch_bounds__(256) p1b(const void* __restrict__ x,
                    const void* __restrict__ kn,
                    const void* __restrict__ qn,
                    const void* __restrict__ aw,
                    const void* __restrict__ tw,
                    const void* __restrict__ ew,
                    float* __restrict__ ws){
  int f = ((const int*)(ws+OFF_FLAG))[0];
  int tok = blockIdx.x; int tid = threadIdx.x;
  __shared__ float sm[8];
  float* krow = ws + OFF_K + (size_t)tok*512;
  float* qrow = ws + OFF_Q + (size_t)tok*512;
  float a = krow[tid], b = krow[tid+256];
  float ss = blockReduceSum(a*a+b*b, sm);
  float n = rsqrtf(ss*(1.f/512.f) + 1e-6f);
  float k1v = a*n*ldin(kn,tid,f);
  float k2v = b*n*ldin(kn,tid+256,f);
  krow[tid]=k1v; krow[tid+256]=k2v;
  float kn2 = blockReduceSum(k1v*k1v+k2v*k2v, sm);
  if(tid==0) ws[OFF_KN2+tok]=kn2;
  a = qrow[tid]; b = qrow[tid+256];
  ss = blockReduceSum(a*a+b*b, sm);
  n = rsqrtf(ss*(1.f/512.f)+1e-6f);
  qrow[tid]=a*n*ldin(qn,tid,f);
  qrow[tid+256]=b*n*ldin(qn,tid+256,f);
  float x1=ldin(x,(size_t)tok*512+tid,f), x2=ldin(x,(size_t)tok*512+tid+256,f);
  float td = blockReduceSum(x1*ldin(tw,tid,f) + x2*ldin(tw,tid+256,f), sm);
  float ad = blockReduceSum(x1*ldin(aw,tid,f) + x2*ldin(aw,tid+256,f), sm);
  float ed = blockReduceSum(x1*ldin(ew,tid,f) + x2*ldin(ew,tid+256,f), sm);
  if(tid==0){
    ws[OFF_TH+tok] = 0.01f/(1.f+expf(-td));
    ws[OFF_AL+tok] = 1.f/(1.f+expf(-ad));
    ws[OFF_ET+tok] = 1.f/(1.f+expf(-ed));
  }
}

// ---------------- K1: update W1(+ln); z-partials for chunk c ----------------
// grid (513,4): bx<512: dt-tile = bx&3 (128 cols), i-tile = bx>>2 (8 rows). bx==512: ln.
__global__ void __launch_bounds__(256) k1_w1(float* __restrict__ ws, int c){
  unsigned short* bsw1 = (unsigned short*)(ws + OFF_BST);
  unsigned short* bmw1 = bsw1 + STSZ;
  int b = blockIdx.y, bx = blockIdx.x, tid = threadIdx.x;
  __shared__ float sE[32], sC[32], scal[3];
  if(c>0){
    const float* slab = ws + OFF_SLAB + ((long)(c-1)*B_ + b)*SLABSTR;
    if(tid<32){ sE[tid]=slab[128+tid]; sC[tid]=slab[160+tid]; }
    if(tid>=32 && tid<35) scal[tid-32]=slab[192+(tid-32)];
  }
  __syncthreads();
  float PE = c>0? scal[0]:1.f, PB = c>0? scal[1]:1.f, Q = c>0? scal[2]:0.f;
  if(bx==512){
    if(c>0){
      for(int d=tid; d<512; d+=256){
        float gE=0,gC=0;
        for(int u=0;u<32;u++){
          float dl = ws[OFF_DLN + ((size_t)(b*32+u))*512 + d];
          gE += sE[u]*dl; gC += sC[u]*dl;
        }
        size_t ix = OFF_SLN + (size_t)b*512 + d;
        float sv=ws[ix], mv=ws[ix + (OFF_MLN-OFF_SLN)];
        ws[ix] = PE*sv - gE;
        ws[ix + (OFF_MLN-OFF_SLN)] = PB*mv + Q*sv - gC;
      }
    }
    return;
  }
  __shared__ __align__(16) float kp[32][132], kc[32][132], mt[8][132];
  __shared__ float aE[8][32], aC[8][32];
  int dt = (bx&3)*128;
  int i0 = (bx>>2)*8;
  int r = tid>>5, l = tid&31;
  if(c>0){
    float dv = ws[OFF_DHP + ((size_t)(b*I_ + i0 + r))*32 + l];
    aE[r][l] = sE[l]*dv; aC[r][l] = sC[l]*dv;
  }
  const float* Kbase = ws + OFF_K + (size_t)b*S_*D_;
  #pragma unroll
  for(int q=0;q<4;q++){
    int f4id = tid + 256*q;
    int u = f4id>>5, dq = f4id&31;
    if(c>0) *(float4*)&kp[u][dq*4] = *(const float4*)(Kbase + (size_t)((c-1)*32+u)*512 + dt + dq*4);
    if(c<16) *(float4*)&kc[u][dq*4] = *(const float4*)(Kbase + (size_t)(c*32+u)*512 + dt + dq*4);
  }
  size_t six = ((size_t)(b*I_ + i0 + r))*512 + dt + l*4;
  ushort4 sv4={0,0,0,0}, mv4;
  if(c>0) sv4 = *(ushort4*)(bsw1 + six);
  mv4 = *(ushort4*)(bmw1 + six);
  __syncthreads();
  {
    float4 nm;
    if(c>0){
      float4 sv = u42f4(sv4), mv = u42f4(mv4);
      float4 gE={0,0,0,0}, gC={0,0,0,0};
      #pragma unroll
      for(int u=0;u<32;u++){
        float4 kv = *(float4*)&kp[u][l*4];
        float ae = aE[r][u], ac = aC[r][u];
        gE.x += ae*kv.x; gE.y += ae*kv.y; gE.z += ae*kv.z; gE.w += ae*kv.w;
        gC.x += ac*kv.x; gC.y += ac*kv.y; gC.z += ac*kv.z; gC.w += ac*kv.w;
      }
      float4 ns;
      ns.x = PE*sv.x - gE.x; ns.y = PE*sv.y - gE.y; ns.z = PE*sv.z - gE.z; ns.w = PE*sv.w - gE.w;
      nm.x = PB*mv.x + Q*sv.x - gC.x; nm.y = PB*mv.y + Q*sv.y - gC.y;
      nm.z = PB*mv.z + Q*sv.z - gC.z; nm.w = PB*mv.w + Q*sv.w - gC.w;
      *(ushort4*)(bsw1 + six) = f42u4(ns);
      *(ushort4*)(bmw1 + six) = f42u4(nm);
    } else {
      nm = u42f4(mv4);
    }
    *(float4*)&mt[r][l*4] = nm;
  }
  __syncthreads();
  if(c<16){
    float z = 0.f;
    #pragma unroll
    for(int d4=0; d4<32; d4++){
      float4 m4 = *(float4*)&mt[r][d4*4];
      float4 k4 = *(float4*)&kc[l][d4*4];     // l = token
      z += m4.x*k4.x + m4.y*k4.y + m4.z*k4.z + m4.w*k4.w;
    }
    ws[OFF_ZP + (size_t)(bx&3)*ZPSZ + ((size_t)(b*I_ + i0 + r))*32 + l] = z;
  }
}

// ---------------- K2: update W2; o-partials = M2@h_c ----------------
// grid (512,4): it-tile = bx&7 (128 i), d-tile = bx>>3 (8 d-rows).
__global__ void __launch_bounds__(256) k2_w2(float* __restrict__ ws, int c){
  unsigned short* bsw2 = (unsigned short*)(ws + OFF_BST) + (size_t)2*STSZ;
  unsigned short* bmw2 = bsw2 + STSZ;
  int b = blockIdx.y, bx = blockIdx.x, tid = threadIdx.x;
  int it0 = (bx&7)*128;
  int d0 = (bx>>3)*8;
  int dtile0 = (bx>>3)==0;
  __shared__ float sE[32], sC[32], scal[3];
  __shared__ __align__(16) float hp[32][132], hc[32][132], mt2[8][132];
  __shared__ float aE[8][32], aC[8][32];
  int r = tid>>5, l = tid&31;
  if(c>0){
    const float* slab = ws + OFF_SLAB + ((long)(c-1)*B_+b)*SLABSTR;
    if(tid<32){ sE[tid]=slab[128+tid]; sC[tid]=slab[160+tid]; }
    if(tid>=32&&tid<35) scal[tid-32]=slab[192+tid-32];
    __syncthreads();
    float dv = ws[OFF_DO + ((size_t)(b*32+l))*512 + d0 + r];
    aE[r][l] = sE[l]*dv; aC[r][l] = sC[l]*dv;
  }
  __syncthreads();
  float PE = c>0?scal[0]:1.f, PB=c>0?scal[1]:1.f, Q=c>0?scal[2]:0.f;
  const float* hprev = ws + OFF_H2 + (size_t)((c-1)&1)*HSZ;
  float* hcur = ws + OFF_H2 + (size_t)(c&1)*HSZ;
  #pragma unroll
  for(int q=0;q<4;q++){
    int f4id = tid + 256*q;
    int ii = f4id>>3, tq = f4id&7;
    size_t base = (size_t)(b*I_ + it0 + ii)*32 + tq*4;
    if(c>0){
      float4 v = *(const float4*)(hprev + base);
      hp[tq*4+0][ii]=v.x; hp[tq*4+1][ii]=v.y; hp[tq*4+2][ii]=v.z; hp[tq*4+3][ii]=v.w;
    }
    if(c<16){
      float4 z0 = *(const float4*)(ws + OFF_ZP + (size_t)0*ZPSZ + base);
      float4 z1 = *(const float4*)(ws + OFF_ZP + (size_t)1*ZPSZ + base);
      float4 z2 = *(const float4*)(ws + OFF_ZP + (size_t)2*ZPSZ + base);
      float4 z3 = *(const float4*)(ws + OFF_ZP + (size_t)3*ZPSZ + base);
      float4 zz; zz.x=z0.x+z1.x+z2.x+z3.x; zz.y=z0.y+z1.y+z2.y+z3.y;
      zz.z=z0.z+z1.z+z2.z+z3.z; zz.w=z0.w+z1.w+z2.w+z3.w;
      float4 h;
      h.x = zz.x/(1.f+expf(-zz.x)); h.y = zz.y/(1.f+expf(-zz.y));
      h.z = zz.z/(1.f+expf(-zz.z)); h.w = zz.w/(1.f+expf(-zz.w));
      hc[tq*4+0][ii]=h.x; hc[tq*4+1][ii]=h.y; hc[tq*4+2][ii]=h.z; hc[tq*4+3][ii]=h.w;
      if(dtile0) *(float4*)(hcur + base) = h;
    }
  }
  size_t six = ((size_t)(b*D_ + d0 + r))*1024 + it0 + l*4;
  ushort4 sv4={0,0,0,0}, mv4;
  if(c>0) sv4 = *(ushort4*)(bsw2 + six);
  mv4 = *(ushort4*)(bmw2 + six);
  __syncthreads();
  {
    float4 nm;
    if(c>0){
      float4 sv = u42f4(sv4), mv = u42f4(mv4);
      float4 gE={0,0,0,0}, gC={0,0,0,0};
      #pragma unroll
      for(int u=0;u<32;u++){
        float4 hv = *(float4*)&hp[u][l*4];
        float ae = aE[r][u], ac = aC[r][u];
        gE.x += ae*hv.x; gE.y += ae*hv.y; gE.z += ae*hv.z; gE.w += ae*hv.w;
        gC.x += ac*hv.x; gC.y += ac*hv.y; gC.z += ac*hv.z; gC.w += ac*hv.w;
      }
      float4 ns;
      ns.x = PE*sv.x - gE.x; ns.y = PE*sv.y - gE.y; ns.z = PE*sv.z - gE.z; ns.w = PE*sv.w - gE.w;
      nm.x = PB*mv.x + Q*sv.x - gC.x; nm.y = PB*mv.y + Q*sv.y - gC.y;
      nm.z = PB*mv.z + Q*sv.z - gC.z; nm.w = PB*mv.w + Q*sv.w - gC.w;
      *(ushort4*)(bsw2 + six) = f42u4(ns);
      *(ushort4*)(bmw2 + six) = f42u4(nm);
    } else {
      nm = u42f4(mv4);
    }
    *(float4*)&mt2[r][l*4] = nm;
  }
  __syncthreads();
  if(c<16){
    float o = 0.f;
    #pragma unroll
    for(int i4=0;i4<32;i4++){
      float4 m4 = *(float4*)&mt2[r][i4*4];
      float4 h4 = *(float4*)&hc[l][i4*4];   // l = token
      o += m4.x*h4.x + m4.y*h4.y + m4.z*h4.z + m4.w*h4.w;
    }
    ws[OFF_OBP + (size_t)(bx&7)*DOSZ + ((size_t)(b*32+l))*512 + d0 + r] = o;
  }
}

// ---------------- K3: per-token rms backward (+ o gather, + h-norms) ----------------
__global__ void __launch_bounds__(256) k3_rms(float* __restrict__ ws, int c){
  int t = blockIdx.x, b = blockIdx.y, tid=threadIdx.x;
  __shared__ float sm[8];
  int tok = b*S_ + c*32 + t;
  const float* krow = ws + OFF_K + (size_t)tok*512;
  const float* vrow = ws + OFF_V + (size_t)tok*512;
  const float* lrow = ws + OFF_MLN + (size_t)b*512;
  float th = ws[OFF_TH + tok];
  float o1=0.f, o2=0.f;
  #pragma unroll
  for(int p=0;p<8;p++){
    const float* ob = ws + OFF_OBP + (size_t)p*DOSZ + ((size_t)(b*32+t))*512;
    o1 += ob[tid]; o2 += ob[tid+256];
  }
  // hn = |h_c(tok)|^2 from H2 cur
  const float* hcur = ws + OFF_H2 + (size_t)(c&1)*HSZ;
  float hsq=0.f;
  for(int i=tid;i<I_;i+=256){ float h = hcur[(size_t)(b*I_+i)*32 + t]; hsq += h*h; }
  float hn = blockReduceSum(hsq, sm);
  float mu = blockReduceSum(o1*o1+o2*o2, sm)*(1.f/512.f);
  float n = rsqrtf(mu + 1e-6f);
  float l1=lrow[tid], l2=lrow[tid+256];
  float k1=krow[tid], k2=krow[tid+256];
  float v1=vrow[tid], v2=vrow[tid+256];
  float c2 = 2.f*th*(1.f/512.f);
  float u1 = c2*(k1 + o1*n*l1 - v1);
  float u2 = c2*(k2 + o2*n*l2 - v2);
  float s1 = blockReduceSum(u1*l1*o1 + u2*l2*o2, sm);
  float dln1 = u1*o1*n, dln2v = u2*o2*n;
  float f = n*n*n*s1*(1.f/512.f);
  float do1 = n*l1*u1 - f*o1;
  float do2 = n*l2*u2 - f*o2;
  float don2 = blockReduceSum(do1*do1+do2*do2, sm);
  float dl2s = blockReduceSum(dln1*dln1+dln2v*dln2v, sm);
  float* dorow = ws + OFF_DO + ((size_t)(b*32+t))*512;
  float* dlrow = ws + OFF_DLN + ((size_t)(b*32+t))*512;
  dorow[tid]=do1; dorow[tid+256]=do2;
  dlrow[tid]=dln1; dlrow[tid+256]=dln2v;
  if(tid==0){
    float* slab = ws + OFF_SLAB + ((size_t)c*B_+b)*SLABSTR;
    slab[0+t]=hn; slab[64+t]=don2; slab[96+t]=dl2s;
  }
}

// ---------------- K4: dh = M2^T do, dhp, grad-norm + scan scalars ----------------
// grid (128,4): 8 i-rows per block.
__global__ void __launch_bounds__(256) k4_dh(float* __restrict__ ws, int c){
  unsigned short* bmw2 = (unsigned short*)(ws + OFF_BST) + (size_t)3*STSZ;
  int bx = blockIdx.x, b = blockIdx.y, tid = threadIdx.x;
  int i0 = bx*8;
  __shared__ __align__(16) float dol[32][132], m2[8][132];
  __shared__ float red[32], coefl[32], bsufl[32];
  __shared__ int lastf;
  int r = tid>>5, t = tid&31;
  float dh = 0.f;
  for(int dt=0; dt<512; dt+=128){
    #pragma unroll
    for(int q=0;q<4;q++){
      int f4id = tid + 256*q;
      int tt = f4id>>5, dq = f4id&31;
      *(float4*)&dol[tt][dq*4] = *(const float4*)(ws + OFF_DO + (size_t)(b*32+tt)*512 + dt + dq*4);
    }
    {
      int dd = tid>>1, iq = tid&1;
      float4 v = u42f4(*(const ushort4*)(bmw2 + (size_t)(b*D_+dt+dd)*1024 + i0 + iq*4));
      m2[iq*4+0][dd]=v.x; m2[iq*4+1][dd]=v.y; m2[iq*4+2][dd]=v.z; m2[iq*4+3][dd]=v.w;
    }
    __syncthreads();
    #pragma unroll
    for(int d4=0; d4<32; d4++){
      float4 dv = *(float4*)&dol[t][d4*4];
      float4 ma = *(float4*)&m2[r][d4*4];
      dh += ma.x*dv.x + ma.y*dv.y + ma.z*dv.z + ma.w*dv.w;
    }
    __syncthreads();
  }
  size_t zb = (size_t)(b*I_ + i0 + r)*32 + t;
  float z = ws[OFF_ZP + (size_t)0*ZPSZ + zb] + ws[OFF_ZP + (size_t)1*ZPSZ + zb]
          + ws[OFF_ZP + (size_t)2*ZPSZ + zb] + ws[OFF_ZP + (size_t)3*ZPSZ + zb];
  float s0 = 1.f/(1.f+expf(-z));
  float dp = dh * s0*(1.f + z*(1.f-s0));
  ws[OFF_DHP+zb] = dp;
  if(tid<32) red[tid]=0.f;
  __syncthreads();
  atomicAdd(&red[t], dp*dp);
  __syncthreads();
  float* slab = ws + OFF_SLAB + ((size_t)c*B_+b)*SLABSTR;
  if(tid<32) atomicAdd(&slab[32+tid], red[tid]);
  __threadfence();
  __syncthreads();
  if(tid==0){
    int* tick = (int*)(ws+OFF_TICK);
    lastf = (atomicAdd(&tick[c*B_+b],1) == 127) ? 1 : 0;
  }
  __syncthreads();
  if(!lastf) return;
  if(tid<32){
    float sqd = atomicAdd(&slab[32+tid], 0.f);
    float hn  = slab[0+tid];
    float don2 = slab[64+tid], dl2 = slab[96+tid];
    float kn2 = ws[OFF_KN2 + b*S_ + c*32 + tid];
    float sq = sqd*kn2 + don2*hn + dl2;
    coefl[tid] = fminf(1.f/(sqrtf(sq)+1e-6f), 1.f);
  }
  __syncthreads();
  if(tid==0){
    const float* eta = ws + OFF_ET + b*S_ + c*32;
    const float* alp = ws + OFF_AL + b*S_ + c*32;
    float Esuf=1.f, Bsuf=1.f, cu=1.f;
    for(int u=31;u>=0;u--){
      if(u<31){
        float e1 = eta[u+1], b1 = 1.f-alp[u+1];
        Esuf *= e1; Bsuf *= b1;
        cu = Bsuf + e1*cu;
      }
      bsufl[u]=Bsuf;
      slab[128+u] = Esuf*coefl[u];
      slab[160+u] = cu*coefl[u];
    }
    float PE = Esuf*eta[0];
    float PB = Bsuf*(1.f-alp[0]);
    float Q=0.f, Epre=1.f;
    for(int t2=0;t2<32;t2++){ Epre *= eta[t2]; Q += bsufl[t2]*Epre; }
    slab[192]=PE; slab[193]=PB; slab[194]=Q;
  }
}

// ---------------- R1: hq = silu(q @ M1^T) ----------------
__global__ void __launch_bounds__(256) r1_gemm(float* __restrict__ ws){
  unsigned short* bmw1 = (unsigned short*)(ws + OFF_BST) + STSZ;
  int b = blockIdx.z;
  int s0 = blockIdx.x*64, i0 = blockIdx.y*64;
  __shared__ __align__(16) float qa[32][68], wa[32][68];
  float acc[4][4]={};
  int tx = threadIdx.x&15, ty = threadIdx.x>>4;
  const float* qb = ws + OFF_Q + (size_t)b*S_*D_;
  const unsigned short* w1b = bmw1 + (size_t)b*I_*D_;
  for(int k0=0;k0<512;k0+=32){
    #pragma unroll
    for(int q=0;q<2;q++){
      int f4id = threadIdx.x + 256*q;
      int row = f4id>>3, kq = f4id&7;
      float4 v = *(const float4*)(qb + (size_t)(s0+row)*512 + k0 + kq*4);
      qa[kq*4+0][row]=v.x; qa[kq*4+1][row]=v.y; qa[kq*4+2][row]=v.z; qa[kq*4+3][row]=v.w;
      float4 w = u42f4(*(const ushort4*)(w1b + (size_t)(i0+row)*512 + k0 + kq*4));
      wa[kq*4+0][row]=w.x; wa[kq*4+1][row]=w.y; wa[kq*4+2][row]=w.z; wa[kq*4+3][row]=w.w;
    }
    __syncthreads();
    #pragma unroll
    for(int kk=0;kk<32;kk++){
      float4 a4 = *(float4*)&qa[kk][ty*4];
      float4 b4 = *(float4*)&wa[kk][tx*4];
      float a_[4]={a4.x,a4.y,a4.z,a4.w}, b_[4]={b4.x,b4.y,b4.z,b4.w};
      #pragma unroll
      for(int i=0;i<4;i++)
        #pragma unroll
        for(int j=0;j<4;j++) acc[i][j]+=a_[i]*b_[j];
    }
    __syncthreads();
  }
  float* hq = ws + OFF_HQ + (size_t)b*S_*I_;
  #pragma unroll
  for(int i=0;i<4;i++){
    float4 o4;
    o4.x = acc[i][0]/(1.f+expf(-acc[i][0])); o4.y = acc[i][1]/(1.f+expf(-acc[i][1]));
    o4.z = acc[i][2]/(1.f+expf(-acc[i][2])); o4.w = acc[i][3]/(1.f+expf(-acc[i][3]));
    *(float4*)(hq + (size_t)(s0+ty*4+i)*1024 + i0 + tx*4) = o4;
  }
}

// ---------------- R2: oret = hq @ M2^T ----------------
__global__ void __launch_bounds__(256) r2_gemm(float* __restrict__ ws){
  unsigned short* bmw2 = (unsigned short*)(ws + OFF_BST) + (size_t)3*STSZ;
  int b=blockIdx.z;
  int s0=blockIdx.x*64, d0=blockIdx.y*64;
  __shared__ __align__(16) float ha[32][68], wa[32][68];
  float acc[4][4]={};
  int tx=threadIdx.x&15, ty=threadIdx.x>>4;
  const float* hq = ws + OFF_HQ + (size_t)b*S_*I_;
  const unsigned short* w2b = bmw2 + (size_t)b*D_*I_;
  for(int k0=0;k0<1024;k0+=32){
    #pragma unroll
    for(int q=0;q<2;q++){
      int f4id = threadIdx.x + 256*q;
      int row = f4id>>3, kq = f4id&7;
      float4 v = *(const float4*)(hq + (size_t)(s0+row)*1024 + k0 + kq*4);
      ha[kq*4+0][row]=v.x; ha[kq*4+1][row]=v.y; ha[kq*4+2][row]=v.z; ha[kq*4+3][row]=v.w;
      float4 w = u42f4(*(const ushort4*)(w2b + (size_t)(d0+row)*1024 + k0 + kq*4));
      wa[kq*4+0][row]=w.x; wa[kq*4+1][row]=w.y; wa[kq*4+2][row]=w.z; wa[kq*4+3][row]=w.w;
    }
    __syncthreads();
    #pragma unroll
    for(int kk=0;kk<32;kk++){
      float4 a4 = *(float4*)&ha[kk][ty*4];
      float4 b4 = *(float4*)&wa[kk][tx*4];
      float a_[4]={a4.x,a4.y,a4.z,a4.w}, b_[4]={b4.x,b4.y,b4.z,b4.w};
      #pragma unroll
      for(int i=0;i<4;i++)
        #pragma unroll
        for(int j=0;j<4;j++) acc[i][j]+=a_[i]*b_[j];
    }
    __syncthreads();
  }
  float* od = ws + OFF_ORET + (size_t)b*S_*D_;
  #pragma unroll
  for(int i=0;i<4;i++){
    float4 o4 = {acc[i][0],acc[i][1],acc[i][2],acc[i][3]};
    *(float4*)(od + (size_t)(s0+ty*4+i)*512 + d0 + tx*4) = o4;
  }
}

// ---------------- R3: out = q + rms(oret, Mln) ----------------
__global__ void __launch_bounds__(256) r3_out(float* __restrict__ ws, void* __restrict__ out){
  int f = ((const int*)(ws+OFF_FLAG))[0];
  int tok=blockIdx.x, tid=threadIdx.x;
  int b = tok >> 9;
  __shared__ float sm[8];
  const float* orow = ws + OFF_ORET + (size_t)tok*512;
  const float* qrow = ws + OFF_Q + (size_t)tok*512;
  const float* lrow = ws + OFF_MLN + (size_t)b*512;
  float o1=orow[tid], o2=orow[tid+256];
  float mu = blockReduceSum(o1*o1+o2*o2, sm)*(1.f/512.f);
  float n = rsqrtf(mu+1e-6f);
  float r1v = qrow[tid]     + o1*n*lrow[tid];
  float r2v = qrow[tid+256] + o2*n*lrow[tid+256];
  if(f){
    ((float*)out)[(size_t)tok*512+tid]     = r1v;
    ((float*)out)[(size_t)tok*512+tid+256] = r2v;
  } else {
    ((__hip_bfloat16*)out)[(size_t)tok*512+tid]     = __float2bfloat16(r1v);
    ((__hip_bfloat16*)out)[(size_t)tok*512+tid+256] = __float2bfloat16(r2v);
  }
}

extern "C" void kernel_launch(void* const* d_in, const int* in_sizes, int n_in,
                              void* d_out, int out_size, void* d_ws, size_t ws_size,
                              hipStream_t stream) {
  const void* x  = d_in[0];
  const void* wq = d_in[1];
  const void* wk = d_in[2];
  const void* wv = d_in[3];
  const void* qn = d_in[4];
  const void* kn = d_in[5];
  const void* aw = d_in[6];
  const void* tw = d_in[7];
  const void* ew = d_in[8];
  const void* w1 = d_in[9];
  const void* w2 = d_in[10];
  const void* ln = d_in[11];
  float* ws = (float*)d_ws;

  d0_detect<<<1,64,0,stream>>>(x, ws);
  p0_init<<<2048,256,0,stream>>>(ws, w1, w2, ln);
  p1a<<<dim3(32,8,3),256,0,stream>>>(x, wk, wv, wq, ws);
  p1b<<<2048,256,0,stream>>>(x, kn, qn, aw, tw, ew, ws);
  for(int c=0;c<=16;c++){
    k1_w1<<<dim3(513,4),256,0,stream>>>(ws, c);
    k2_w2<<<dim3(512,4),256,0,stream>>>(ws, c);
    if(c<16){
      k3_rms<<<dim3(32,4),256,0,stream>>>(ws, c);
      k4_dh<<<dim3(128,4),256,0,stream>>>(ws, c);
    }
  }
  r1_gemm<<<dim3(8,16,4),256,0,stream>>>(ws);
  r2_gemm<<<dim3(8,8,4),256,0,stream>>>(ws);
  r3_out<<<2048,256,0,stream>>>(ws, d_out);
}